// Round 1
// baseline (1831.873 us; speedup 1.0000x reference)
//
#include <hip/hip_runtime.h>

#define N_IN 256
#define N_OUT 64
#define NEG_SLOPE 0.01f

constexpr int ROWS = 32;  // rows of h per block in the GEMM

// ---------------------------------------------------------------------------
// Kernel 1: z = h @ W.T  (fused: s_node = z@a_src, d_node = z@a_dst)
// block = 256 threads = 4 waves; wave w handles rows w*8..w*8+7, lane = out col
// LDS: Wt[k][c] (64 KB, transposed so lane-consecutive c -> conflict-free)
//      hs[ROWS][256] (32 KB)
// ---------------------------------------------------------------------------
__global__ __launch_bounds__(256) void gemm_zsd(
    const float* __restrict__ h, const float* __restrict__ W,
    const float* __restrict__ A,
    float* __restrict__ z, float* __restrict__ s_node, float* __restrict__ d_node,
    int n_nodes)
{
    __shared__ float Wt[N_IN][N_OUT];
    __shared__ float hs[ROWS][N_IN];
    const int t = threadIdx.x;

    // stage W transposed: W is [64][256] row-major; Wt[k][c] = W[c*256+k]
    for (int i = t; i < N_IN * N_OUT; i += 256) {
        int c = i >> 8, k = i & 255;
        Wt[k][c] = W[i];
    }
    const int row0 = blockIdx.x * ROWS;
    const float4* __restrict__ h4 = reinterpret_cast<const float4*>(h + (size_t)row0 * N_IN);
    float4* hs4 = reinterpret_cast<float4*>(&hs[0][0]);
#pragma unroll
    for (int i = 0; i < (ROWS * N_IN / 4) / 256; ++i)
        hs4[i * 256 + t] = h4[i * 256 + t];
    __syncthreads();

    const int c  = t & 63;   // output column
    const int wv = t >> 6;   // wave id -> row group
    const int rbase = wv * 8;

    float acc[8] = {0.f,0.f,0.f,0.f,0.f,0.f,0.f,0.f};
    for (int k = 0; k < N_IN; k += 4) {
        const float w0 = Wt[k+0][c], w1 = Wt[k+1][c], w2 = Wt[k+2][c], w3 = Wt[k+3][c];
#pragma unroll
        for (int r = 0; r < 8; ++r) {
            const float4 hv = *reinterpret_cast<const float4*>(&hs[rbase + r][k]);  // broadcast
            acc[r] = fmaf(hv.x, w0, acc[r]);
            acc[r] = fmaf(hv.y, w1, acc[r]);
            acc[r] = fmaf(hv.z, w2, acc[r]);
            acc[r] = fmaf(hv.w, w3, acc[r]);
        }
    }

    const float a_s = A[c];
    const float a_d = A[N_OUT + c];
#pragma unroll
    for (int r = 0; r < 8; ++r) {
        const int row = row0 + rbase + r;
        z[(size_t)row * N_OUT + c] = acc[r];
        float vs = acc[r] * a_s;
        float vd = acc[r] * a_d;
#pragma unroll
        for (int off = 32; off > 0; off >>= 1) {
            vs += __shfl_down(vs, off);
            vd += __shfl_down(vd, off);
        }
        if (c == 0) { s_node[row] = vs; d_node[row] = vd; }
    }
}

// ---------------------------------------------------------------------------
// Kernel 2: per-edge  p = exp(leakyrelu(s[src]+d[dst])); denom[dst] += p
// (max-subtraction dropped: e ~ N(0,1), exp safe in f32; alpha is identical)
// ---------------------------------------------------------------------------
__global__ __launch_bounds__(256) void edge_pass1(
    const int* __restrict__ src, const int* __restrict__ dst,
    const float* __restrict__ s_node, const float* __restrict__ d_node,
    float* __restrict__ p, float* __restrict__ denom, int n_edges)
{
    int i = blockIdx.x * blockDim.x + threadIdx.x;
    const int stride = gridDim.x * blockDim.x;
    for (; i < n_edges; i += stride) {
        const int s = src[i], d = dst[i];
        float e = s_node[s] + d_node[d];
        e = (e >= 0.f) ? e : NEG_SLOPE * e;
        const float pe = __expf(e);
        p[i] = pe;
        unsafeAtomicAdd(&denom[d], pe);
    }
}

// ---------------------------------------------------------------------------
// Kernel 3: per-edge  out[dst][:] += (p/denom[dst]) * z[src][:]
// 16 lanes per edge, each lane handles 4 consecutive columns (float4 gather)
// ---------------------------------------------------------------------------
__global__ __launch_bounds__(256) void edge_pass2(
    const int* __restrict__ src, const int* __restrict__ dst,
    const float* __restrict__ p, const float* __restrict__ denom,
    const float* __restrict__ z, float* __restrict__ out, int n_edges)
{
    const int tid = blockIdx.x * blockDim.x + threadIdx.x;
    const int lane4 = tid & 15;
    int eidx = tid >> 4;
    const int estride = (gridDim.x * blockDim.x) >> 4;
    for (; eidx < n_edges; eidx += estride) {
        const int s = src[eidx], d = dst[eidx];
        const float dn = denom[d];
        const float w = p[eidx] / (dn > 0.f ? dn : 1.f);
        const float4 zv = reinterpret_cast<const float4*>(z + (size_t)s * N_OUT)[lane4];
        float* o = out + (size_t)d * N_OUT + lane4 * 4;
        unsafeAtomicAdd(o + 0, w * zv.x);
        unsafeAtomicAdd(o + 1, w * zv.y);
        unsafeAtomicAdd(o + 2, w * zv.z);
        unsafeAtomicAdd(o + 3, w * zv.w);
    }
}

// ---------------------------------------------------------------------------
extern "C" void kernel_launch(void* const* d_in, const int* in_sizes, int n_in,
                              void* d_out, int out_size, void* d_ws, size_t ws_size,
                              hipStream_t stream) {
    const float* h = (const float*)d_in[0];
    const float* W = (const float*)d_in[1];
    const float* A = (const float*)d_in[2];
    const int* src = (const int*)d_in[3];
    const int* dst = (const int*)d_in[4];
    float* out = (float*)d_out;

    const int n_nodes = in_sizes[0] / N_IN;
    const int n_edges = in_sizes[3];

    // workspace layout
    float* z      = (float*)d_ws;              // n_nodes*64
    float* s_node = z + (size_t)n_nodes * N_OUT;
    float* d_node = s_node + n_nodes;
    float* p      = d_node + n_nodes;          // n_edges
    float* denom  = p + n_edges;               // n_nodes

    // zero-init accumulators (ws/out are poisoned 0xAA before every call)
    hipMemsetAsync(denom, 0, (size_t)n_nodes * sizeof(float), stream);
    hipMemsetAsync(out, 0, (size_t)out_size * sizeof(float), stream);

    // 1) GEMM + logits
    const int gblocks = n_nodes / ROWS;  // 100000/32 = 3125 exact
    gemm_zsd<<<gblocks, 256, 0, stream>>>(h, W, A, z, s_node, d_node, n_nodes);

    // 2) edge softmax numerator + denominator
    edge_pass1<<<2048, 256, 0, stream>>>(src, dst, s_node, d_node, p, denom, n_edges);

    // 3) weighted scatter-add
    edge_pass2<<<8192, 256, 0, stream>>>(src, dst, p, denom, z, out, n_edges);
}

// Round 5
// 626.287 us; speedup vs baseline: 2.9250x; 2.9250x over previous
//
#include <hip/hip_runtime.h>

#define N_IN 256
#define N_OUT 64
#define NEG_SLOPE 0.01f

constexpr int ROWS = 32;  // rows of h per block in the GEMM

// ---------------------------------------------------------------------------
// Kernel 1: z = h @ W.T  (fused: s_node = z@a_src, d_node = z@a_dst)
// ---------------------------------------------------------------------------
__global__ __launch_bounds__(256) void gemm_zsd(
    const float* __restrict__ h, const float* __restrict__ W,
    const float* __restrict__ A,
    float* __restrict__ z, float* __restrict__ s_node, float* __restrict__ d_node,
    int n_nodes)
{
    __shared__ float Wt[N_IN][N_OUT];
    __shared__ float hs[ROWS][N_IN];
    const int t = threadIdx.x;

    for (int i = t; i < N_IN * N_OUT; i += 256) {
        int c = i >> 8, k = i & 255;
        Wt[k][c] = W[i];
    }
    const int row0 = blockIdx.x * ROWS;
    const float4* __restrict__ h4 = reinterpret_cast<const float4*>(h + (size_t)row0 * N_IN);
    float4* hs4 = reinterpret_cast<float4*>(&hs[0][0]);
#pragma unroll
    for (int i = 0; i < (ROWS * N_IN / 4) / 256; ++i)
        hs4[i * 256 + t] = h4[i * 256 + t];
    __syncthreads();

    const int c  = t & 63;
    const int wv = t >> 6;
    const int rbase = wv * 8;

    float acc[8] = {0.f,0.f,0.f,0.f,0.f,0.f,0.f,0.f};
    for (int k = 0; k < N_IN; k += 4) {
        const float w0 = Wt[k+0][c], w1 = Wt[k+1][c], w2 = Wt[k+2][c], w3 = Wt[k+3][c];
#pragma unroll
        for (int r = 0; r < 8; ++r) {
            const float4 hv = *reinterpret_cast<const float4*>(&hs[rbase + r][k]);
            acc[r] = fmaf(hv.x, w0, acc[r]);
            acc[r] = fmaf(hv.y, w1, acc[r]);
            acc[r] = fmaf(hv.z, w2, acc[r]);
            acc[r] = fmaf(hv.w, w3, acc[r]);
        }
    }

    const float a_s = A[c];
    const float a_d = A[N_OUT + c];
#pragma unroll
    for (int r = 0; r < 8; ++r) {
        const int row = row0 + rbase + r;
        z[(size_t)row * N_OUT + c] = acc[r];
        float vs = acc[r] * a_s;
        float vd = acc[r] * a_d;
#pragma unroll
        for (int off = 32; off > 0; off >>= 1) {
            vs += __shfl_down(vs, off);
            vd += __shfl_down(vd, off);
        }
        if (c == 0) { s_node[row] = vs; d_node[row] = vd; }
    }
}

// ---------------------------------------------------------------------------
// Kernel 2: histogram of dst  (counts must be pre-zeroed)
// ---------------------------------------------------------------------------
__global__ __launch_bounds__(256) void count_dst(
    const int* __restrict__ dst, int* __restrict__ counts, int n_edges)
{
    int i = blockIdx.x * blockDim.x + threadIdx.x;
    const int stride = gridDim.x * blockDim.x;
    for (; i < n_edges; i += stride)
        atomicAdd(&counts[dst[i]], 1);
}

// ---------------------------------------------------------------------------
// Kernel 3a: per-block exclusive scan (in-place) + block totals
// ---------------------------------------------------------------------------
__global__ __launch_bounds__(1024) void scan_block(
    int* __restrict__ data, int* __restrict__ partials, int n)
{
    __shared__ int tmp[1024];
    const int gid = blockIdx.x * 1024 + threadIdx.x;
    const int v = (gid < n) ? data[gid] : 0;
    tmp[threadIdx.x] = v;
    __syncthreads();
    for (int off = 1; off < 1024; off <<= 1) {
        int t = (threadIdx.x >= off) ? tmp[threadIdx.x - off] : 0;
        __syncthreads();
        tmp[threadIdx.x] += t;
        __syncthreads();
    }
    const int incl = tmp[threadIdx.x];
    if (gid < n) data[gid] = incl - v;               // exclusive within block
    if (threadIdx.x == 1023) partials[blockIdx.x] = incl;
}

// Kernel 3b: exclusive scan of block totals (single block, nb <= 128)
__global__ __launch_bounds__(128) void scan_partials(int* __restrict__ partials, int nb)
{
    __shared__ int tmp[128];
    const int v = (threadIdx.x < nb) ? partials[threadIdx.x] : 0;
    tmp[threadIdx.x] = v;
    __syncthreads();
    for (int off = 1; off < 128; off <<= 1) {
        int t = (threadIdx.x >= off) ? tmp[threadIdx.x - off] : 0;
        __syncthreads();
        tmp[threadIdx.x] += t;
        __syncthreads();
    }
    if (threadIdx.x < nb) partials[threadIdx.x] = tmp[threadIdx.x] - v;
}

// Kernel 3c: add scanned block bases -> full exclusive scan (segment starts)
__global__ __launch_bounds__(256) void scan_add_base(
    int* __restrict__ data, const int* __restrict__ partials, int n)
{
    const int gid = blockIdx.x * blockDim.x + threadIdx.x;
    if (gid < n) data[gid] += partials[gid >> 10];
}

// ---------------------------------------------------------------------------
// Kernel 4: compute p = exp(leakyrelu(s[src]+d[dst])) and scatter {src,p}
// into dst-sorted order. cursor[] starts as segment starts; after this
// kernel cursor[d] == segment end of d (exclusive).
// ---------------------------------------------------------------------------
__global__ __launch_bounds__(256) void edge_scatter(
    const int* __restrict__ src, const int* __restrict__ dst,
    const float* __restrict__ s_node, const float* __restrict__ d_node,
    int* __restrict__ cursor, int2* __restrict__ edges, int n_edges)
{
    int i = blockIdx.x * blockDim.x + threadIdx.x;
    const int stride = gridDim.x * blockDim.x;
    for (; i < n_edges; i += stride) {
        const int s = src[i], d = dst[i];
        float e = s_node[s] + d_node[d];
        e = (e >= 0.f) ? e : NEG_SLOPE * e;
        const float pe = __expf(e);
        const int pos = atomicAdd(&cursor[d], 1);
        edges[pos] = make_int2(s, __float_as_int(pe));
    }
}

// ---------------------------------------------------------------------------
// Kernel 5: one wave per dst node; lane = output column.
// acc[c] = sum_e p_e * z[src_e][c];  denom = sum_e p_e;  out = acc/denom.
// segend[d] = end of segment d; start = segend[d-1] (0 for d==0).
// ---------------------------------------------------------------------------
__global__ __launch_bounds__(256) void gather_accum(
    const int2* __restrict__ edges, const int* __restrict__ segend,
    const float* __restrict__ z, float* __restrict__ out, int n_nodes)
{
    const int wave = (blockIdx.x * 256 + threadIdx.x) >> 6;
    const int lane = threadIdx.x & 63;
    if (wave >= n_nodes) return;
    const int end   = segend[wave];
    const int start = (wave == 0) ? 0 : segend[wave - 1];

    float acc = 0.f, denom = 0.f;
    int i = start;
    for (; i + 1 < end; i += 2) {
        const int2 e0 = edges[i];
        const int2 e1 = edges[i + 1];
        const float z0 = z[(size_t)e0.x * N_OUT + lane];
        const float z1 = z[(size_t)e1.x * N_OUT + lane];
        const float p0 = __int_as_float(e0.y);
        const float p1 = __int_as_float(e1.y);
        denom += p0 + p1;
        acc = fmaf(p0, z0, acc);
        acc = fmaf(p1, z1, acc);
    }
    if (i < end) {
        const int2 e0 = edges[i];
        const float p0 = __int_as_float(e0.y);
        denom += p0;
        acc = fmaf(p0, z[(size_t)e0.x * N_OUT + lane], acc);
    }
    out[(size_t)wave * N_OUT + lane] = (end > start) ? acc / denom : 0.f;
}

// ---------------------------------------------------------------------------
extern "C" void kernel_launch(void* const* d_in, const int* in_sizes, int n_in,
                              void* d_out, int out_size, void* d_ws, size_t ws_size,
                              hipStream_t stream) {
    const float* h = (const float*)d_in[0];
    const float* W = (const float*)d_in[1];
    const float* A = (const float*)d_in[2];
    const int* src = (const int*)d_in[3];
    const int* dst = (const int*)d_in[4];
    float* out = (float*)d_out;

    const int n_nodes = in_sizes[0] / N_IN;
    const int n_edges = in_sizes[3];

    // workspace layout (all offsets keep 8B alignment for the int2 array)
    char* ws = (char*)d_ws;
    float* z      = (float*)ws;                    ws += (size_t)n_nodes * N_OUT * 4;
    float* s_node = (float*)ws;                    ws += (size_t)n_nodes * 4;
    float* d_node = (float*)ws;                    ws += (size_t)n_nodes * 4;
    int*   counts = (int*)ws;                      ws += (size_t)n_nodes * 4;   // -> offsets -> segends
    int*   parts  = (int*)ws;                      ws += 512;
    int2*  edges  = (int2*)ws;

    const int nb_scan = (n_nodes + 1023) / 1024;   // 98 <= 128

    // zero the histogram only (kernel 5 writes every out element)
    hipMemsetAsync(counts, 0, (size_t)n_nodes * sizeof(int), stream);

    // 1) GEMM + logits
    gemm_zsd<<<n_nodes / ROWS, 256, 0, stream>>>(h, W, A, z, s_node, d_node, n_nodes);

    // 2) dst histogram
    count_dst<<<1024, 256, 0, stream>>>(dst, counts, n_edges);

    // 3) exclusive scan -> segment starts
    scan_block<<<nb_scan, 1024, 0, stream>>>(counts, parts, n_nodes);
    scan_partials<<<1, 128, 0, stream>>>(parts, nb_scan);
    scan_add_base<<<(n_nodes + 255) / 256, 256, 0, stream>>>(counts, parts, n_nodes);

    // 4) compute p and scatter into dst-sorted order (counts -> segment ends)
    edge_scatter<<<2048, 256, 0, stream>>>(src, dst, s_node, d_node, counts, edges, n_edges);

    // 5) per-dst register accumulate, single write of out
    gather_accum<<<(n_nodes * 64 + 255) / 256, 256, 0, stream>>>(edges, counts, z, out, n_nodes);
}

// Round 6
// 417.954 us; speedup vs baseline: 4.3830x; 1.4985x over previous
//
#include <hip/hip_runtime.h>

#define N_IN 256
#define N_OUT 64
#define NEG_SLOPE 0.01f

typedef __attribute__((ext_vector_type(8))) short short8v;   // 8 bf16
typedef __attribute__((ext_vector_type(4))) float float4v;   // MFMA acc

__device__ inline short f32_to_bf16_rtne(float f) {
    unsigned u = __float_as_uint(f);
    unsigned r = (u + 0x7FFFu + ((u >> 16) & 1u)) >> 16;
    return (short)r;
}

// ---------------------------------------------------------------------------
// Kernel 1: z = h @ W.T via bf16 MFMA, fused logits s_node/d_node.
// 64 rows/block, 256 thr = 4 waves; wave w owns rows w*16..w*16+15, all 64 cols.
// LDS: hA[64][264] bf16 (33KB) + wB[64][264] bf16 (33KB) -> 2 blocks/CU.
// Pad 264: row stride 132 dwords === 4 (mod 32) -> b128 reads/writes spread
// uniformly over banks (no conflicts).
// Fragment layout (16x16x32_bf16): A row = lane&15, k = (lane>>4)*8+j;
// B col = lane&15 (wB row = output col); C/D col = lane&15,
// row = (lane>>4)*4 + reg  [verified m89].
// ---------------------------------------------------------------------------
constexpr int GM = 64;
constexpr int KP = 264;   // padded K (bf16 units); 528 B row stride, 16B-aligned

__global__ __launch_bounds__(256) void gemm_zsd_mfma(
    const float* __restrict__ h, const float* __restrict__ W,
    const float* __restrict__ A,
    float* __restrict__ z, float* __restrict__ s_node, float* __restrict__ d_node,
    int n_nodes)
{
    __shared__ short hA[GM * KP];
    __shared__ short wB[N_OUT * KP];
    const int t = threadIdx.x;
    const int row0 = blockIdx.x * GM;

    // ---- stage h tile and W, f32 -> bf16(RTNE), 8 cols (16B) per write ----
    for (int j = 0; j < 8; ++j) {
        const int f  = j * 256 + t;      // 8-col group index
        const int r  = f >> 5;           // row 0..63
        const int c8 = f & 31;           // 8-col group 0..31

        int grow = row0 + r;
        if (grow >= n_nodes) grow = n_nodes - 1;   // clamp (tail block)
        const float4* ph = reinterpret_cast<const float4*>(h + (size_t)grow * N_IN + c8 * 8);
        float4 h0 = ph[0], h1 = ph[1];
        short8v pkh;
        pkh[0] = f32_to_bf16_rtne(h0.x); pkh[1] = f32_to_bf16_rtne(h0.y);
        pkh[2] = f32_to_bf16_rtne(h0.z); pkh[3] = f32_to_bf16_rtne(h0.w);
        pkh[4] = f32_to_bf16_rtne(h1.x); pkh[5] = f32_to_bf16_rtne(h1.y);
        pkh[6] = f32_to_bf16_rtne(h1.z); pkh[7] = f32_to_bf16_rtne(h1.w);
        *reinterpret_cast<short8v*>(&hA[r * KP + c8 * 8]) = pkh;

        const float4* pw = reinterpret_cast<const float4*>(W + (size_t)r * N_IN + c8 * 8);
        float4 w0 = pw[0], w1 = pw[1];
        short8v pkw;
        pkw[0] = f32_to_bf16_rtne(w0.x); pkw[1] = f32_to_bf16_rtne(w0.y);
        pkw[2] = f32_to_bf16_rtne(w0.z); pkw[3] = f32_to_bf16_rtne(w0.w);
        pkw[4] = f32_to_bf16_rtne(w1.x); pkw[5] = f32_to_bf16_rtne(w1.y);
        pkw[6] = f32_to_bf16_rtne(w1.z); pkw[7] = f32_to_bf16_rtne(w1.w);
        *reinterpret_cast<short8v*>(&wB[r * KP + c8 * 8]) = pkw;
    }
    __syncthreads();

    const int w  = t >> 6;    // wave id
    const int l  = t & 63;
    const int lr = l & 15;    // A row / B col / C col within 16
    const int lk = l >> 4;    // k-group (0..3)

    float4v acc[4] = {{0.f,0.f,0.f,0.f},{0.f,0.f,0.f,0.f},
                      {0.f,0.f,0.f,0.f},{0.f,0.f,0.f,0.f}};

    for (int kk = 0; kk < 8; ++kk) {                 // K-steps of 32
        const int kbase = kk * 32 + lk * 8;
        const short8v a = *reinterpret_cast<const short8v*>(&hA[(w * 16 + lr) * KP + kbase]);
#pragma unroll
        for (int n = 0; n < 4; ++n) {
            const short8v b = *reinterpret_cast<const short8v*>(&wB[(n * 16 + lr) * KP + kbase]);
            acc[n] = __builtin_amdgcn_mfma_f32_16x16x32_bf16(a, b, acc[n], 0, 0, 0);
        }
    }

    // ---- epilogue: write z (f32), fused s/d logits ----
    float as[4], ad[4];
#pragma unroll
    for (int n = 0; n < 4; ++n) {
        as[n] = A[n * 16 + lr];
        ad[n] = A[N_OUT + n * 16 + lr];
    }

    float sv[4] = {0.f,0.f,0.f,0.f}, dv[4] = {0.f,0.f,0.f,0.f};
#pragma unroll
    for (int n = 0; n < 4; ++n) {
#pragma unroll
        for (int r = 0; r < 4; ++r) {
            const float v = acc[n][r];
            const int grow = row0 + w * 16 + lk * 4 + r;
            if (grow < n_nodes) z[(size_t)grow * N_OUT + n * 16 + lr] = v;
            sv[r] = fmaf(v, as[n], sv[r]);
            dv[r] = fmaf(v, ad[n], dv[r]);
        }
    }
    // reduce over the 16 lanes (lr) of each lk-group
#pragma unroll
    for (int off = 1; off < 16; off <<= 1) {
#pragma unroll
        for (int r = 0; r < 4; ++r) {
            sv[r] += __shfl_xor(sv[r], off);
            dv[r] += __shfl_xor(dv[r], off);
        }
    }
    if (lr == 0) {
#pragma unroll
        for (int r = 0; r < 4; ++r) {
            const int grow = row0 + w * 16 + lk * 4 + r;
            if (grow < n_nodes) { s_node[grow] = sv[r]; d_node[grow] = dv[r]; }
        }
    }
}

// ---------------------------------------------------------------------------
// Kernel 2: histogram of dst  (counts must be pre-zeroed)
// ---------------------------------------------------------------------------
__global__ __launch_bounds__(256) void count_dst(
    const int* __restrict__ dst, int* __restrict__ counts, int n_edges)
{
    int i = blockIdx.x * blockDim.x + threadIdx.x;
    const int stride = gridDim.x * blockDim.x;
    for (; i < n_edges; i += stride)
        atomicAdd(&counts[dst[i]], 1);
}

// ---------------------------------------------------------------------------
// Kernel 3a: per-block exclusive scan (in-place) + block totals
// ---------------------------------------------------------------------------
__global__ __launch_bounds__(1024) void scan_block(
    int* __restrict__ data, int* __restrict__ partials, int n)
{
    __shared__ int tmp[1024];
    const int gid = blockIdx.x * 1024 + threadIdx.x;
    const int v = (gid < n) ? data[gid] : 0;
    tmp[threadIdx.x] = v;
    __syncthreads();
    for (int off = 1; off < 1024; off <<= 1) {
        int t = (threadIdx.x >= off) ? tmp[threadIdx.x - off] : 0;
        __syncthreads();
        tmp[threadIdx.x] += t;
        __syncthreads();
    }
    const int incl = tmp[threadIdx.x];
    if (gid < n) data[gid] = incl - v;               // exclusive within block
    if (threadIdx.x == 1023) partials[blockIdx.x] = incl;
}

// Kernel 3b: exclusive scan of block totals (single block, nb <= 128)
__global__ __launch_bounds__(128) void scan_partials(int* __restrict__ partials, int nb)
{
    __shared__ int tmp[128];
    const int v = (threadIdx.x < nb) ? partials[threadIdx.x] : 0;
    tmp[threadIdx.x] = v;
    __syncthreads();
    for (int off = 1; off < 128; off <<= 1) {
        int t = (threadIdx.x >= off) ? tmp[threadIdx.x - off] : 0;
        __syncthreads();
        tmp[threadIdx.x] += t;
        __syncthreads();
    }
    if (threadIdx.x < nb) partials[threadIdx.x] = tmp[threadIdx.x] - v;
}

// Kernel 3c: add scanned block bases -> full exclusive scan (segment starts)
__global__ __launch_bounds__(256) void scan_add_base(
    int* __restrict__ data, const int* __restrict__ partials, int n)
{
    const int gid = blockIdx.x * blockDim.x + threadIdx.x;
    if (gid < n) data[gid] += partials[gid >> 10];
}

// ---------------------------------------------------------------------------
// Kernel 4: compute p = exp(leakyrelu(s[src]+d[dst])) and scatter {src,p}
// into dst-sorted order. cursor[] starts as segment starts; after this
// kernel cursor[d] == segment end of d (exclusive).
// ---------------------------------------------------------------------------
__global__ __launch_bounds__(256) void edge_scatter(
    const int* __restrict__ src, const int* __restrict__ dst,
    const float* __restrict__ s_node, const float* __restrict__ d_node,
    int* __restrict__ cursor, int2* __restrict__ edges, int n_edges)
{
    int i = blockIdx.x * blockDim.x + threadIdx.x;
    const int stride = gridDim.x * blockDim.x;
    for (; i < n_edges; i += stride) {
        const int s = src[i], d = dst[i];
        float e = s_node[s] + d_node[d];
        e = (e >= 0.f) ? e : NEG_SLOPE * e;
        const float pe = __expf(e);
        const int pos = atomicAdd(&cursor[d], 1);
        edges[pos] = make_int2(s, __float_as_int(pe));
    }
}

// ---------------------------------------------------------------------------
// Kernel 5: one wave per dst node; lane = output column.
// ---------------------------------------------------------------------------
__global__ __launch_bounds__(256) void gather_accum(
    const int2* __restrict__ edges, const int* __restrict__ segend,
    const float* __restrict__ z, float* __restrict__ out, int n_nodes)
{
    const int wave = (blockIdx.x * 256 + threadIdx.x) >> 6;
    const int lane = threadIdx.x & 63;
    if (wave >= n_nodes) return;
    const int end   = segend[wave];
    const int start = (wave == 0) ? 0 : segend[wave - 1];

    float acc = 0.f, denom = 0.f;
    int i = start;
    for (; i + 1 < end; i += 2) {
        const int2 e0 = edges[i];
        const int2 e1 = edges[i + 1];
        const float z0 = z[(size_t)e0.x * N_OUT + lane];
        const float z1 = z[(size_t)e1.x * N_OUT + lane];
        const float p0 = __int_as_float(e0.y);
        const float p1 = __int_as_float(e1.y);
        denom += p0 + p1;
        acc = fmaf(p0, z0, acc);
        acc = fmaf(p1, z1, acc);
    }
    if (i < end) {
        const int2 e0 = edges[i];
        const float p0 = __int_as_float(e0.y);
        denom += p0;
        acc = fmaf(p0, z[(size_t)e0.x * N_OUT + lane], acc);
    }
    out[(size_t)wave * N_OUT + lane] = (end > start) ? acc / denom : 0.f;
}

// ---------------------------------------------------------------------------
extern "C" void kernel_launch(void* const* d_in, const int* in_sizes, int n_in,
                              void* d_out, int out_size, void* d_ws, size_t ws_size,
                              hipStream_t stream) {
    const float* h = (const float*)d_in[0];
    const float* W = (const float*)d_in[1];
    const float* A = (const float*)d_in[2];
    const int* src = (const int*)d_in[3];
    const int* dst = (const int*)d_in[4];
    float* out = (float*)d_out;

    const int n_nodes = in_sizes[0] / N_IN;
    const int n_edges = in_sizes[3];

    // workspace layout (all offsets keep 8B alignment for the int2 array)
    char* ws = (char*)d_ws;
    float* z      = (float*)ws;                    ws += (size_t)n_nodes * N_OUT * 4;
    float* s_node = (float*)ws;                    ws += (size_t)n_nodes * 4;
    float* d_node = (float*)ws;                    ws += (size_t)n_nodes * 4;
    int*   counts = (int*)ws;                      ws += (size_t)n_nodes * 4;   // -> offsets -> segends
    int*   parts  = (int*)ws;                      ws += 512;
    int2*  edges  = (int2*)ws;

    const int nb_scan = (n_nodes + 1023) / 1024;   // 98 <= 128

    // zero the histogram only (kernel 5 writes every out element)
    hipMemsetAsync(counts, 0, (size_t)n_nodes * sizeof(int), stream);

    // 1) GEMM + logits (bf16 MFMA)
    gemm_zsd_mfma<<<(n_nodes + GM - 1) / GM, 256, 0, stream>>>(h, W, A, z, s_node, d_node, n_nodes);

    // 2) dst histogram
    count_dst<<<1024, 256, 0, stream>>>(dst, counts, n_edges);

    // 3) exclusive scan -> segment starts
    scan_block<<<nb_scan, 1024, 0, stream>>>(counts, parts, n_nodes);
    scan_partials<<<1, 128, 0, stream>>>(parts, nb_scan);
    scan_add_base<<<(n_nodes + 255) / 256, 256, 0, stream>>>(counts, parts, n_nodes);

    // 4) compute p and scatter into dst-sorted order (counts -> segment ends)
    edge_scatter<<<2048, 256, 0, stream>>>(src, dst, s_node, d_node, counts, edges, n_edges);

    // 5) per-dst register accumulate, single write of out
    gather_accum<<<(n_nodes * 64 + 255) / 256, 256, 0, stream>>>(edges, counts, z, out, n_nodes);
}

// Round 7
// 379.399 us; speedup vs baseline: 4.8284x; 1.1016x over previous
//
#include <hip/hip_runtime.h>

#define N_IN 256
#define N_OUT 64
#define NEG_SLOPE 0.01f

typedef __attribute__((ext_vector_type(8))) short short8v;   // 8 bf16
typedef __attribute__((ext_vector_type(4))) float float4v;   // MFMA acc

__device__ inline short f32_to_bf16_rtne(float f) {
    unsigned u = __float_as_uint(f);
    unsigned r = (u + 0x7FFFu + ((u >> 16) & 1u)) >> 16;
    return (short)r;
}

// ---------------------------------------------------------------------------
// Kernel 1: z = h @ W.T via bf16 MFMA, fused logits s_node/d_node.
// ---------------------------------------------------------------------------
constexpr int GM = 64;
constexpr int KP = 264;   // padded K (bf16 units); 528 B row stride, 16B-aligned

__global__ __launch_bounds__(256) void gemm_zsd_mfma(
    const float* __restrict__ h, const float* __restrict__ W,
    const float* __restrict__ A,
    float* __restrict__ z, float* __restrict__ s_node, float* __restrict__ d_node,
    int n_nodes)
{
    __shared__ short hA[GM * KP];
    __shared__ short wB[N_OUT * KP];
    const int t = threadIdx.x;
    const int row0 = blockIdx.x * GM;

    // ---- stage h tile and W, f32 -> bf16(RTNE), 8 cols (16B) per write ----
    for (int j = 0; j < 8; ++j) {
        const int f  = j * 256 + t;      // 8-col group index
        const int r  = f >> 5;           // row 0..63
        const int c8 = f & 31;           // 8-col group 0..31

        int grow = row0 + r;
        if (grow >= n_nodes) grow = n_nodes - 1;   // clamp (tail block)
        const float4* ph = reinterpret_cast<const float4*>(h + (size_t)grow * N_IN + c8 * 8);
        float4 h0 = ph[0], h1 = ph[1];
        short8v pkh;
        pkh[0] = f32_to_bf16_rtne(h0.x); pkh[1] = f32_to_bf16_rtne(h0.y);
        pkh[2] = f32_to_bf16_rtne(h0.z); pkh[3] = f32_to_bf16_rtne(h0.w);
        pkh[4] = f32_to_bf16_rtne(h1.x); pkh[5] = f32_to_bf16_rtne(h1.y);
        pkh[6] = f32_to_bf16_rtne(h1.z); pkh[7] = f32_to_bf16_rtne(h1.w);
        *reinterpret_cast<short8v*>(&hA[r * KP + c8 * 8]) = pkh;

        const float4* pw = reinterpret_cast<const float4*>(W + (size_t)r * N_IN + c8 * 8);
        float4 w0 = pw[0], w1 = pw[1];
        short8v pkw;
        pkw[0] = f32_to_bf16_rtne(w0.x); pkw[1] = f32_to_bf16_rtne(w0.y);
        pkw[2] = f32_to_bf16_rtne(w0.z); pkw[3] = f32_to_bf16_rtne(w0.w);
        pkw[4] = f32_to_bf16_rtne(w1.x); pkw[5] = f32_to_bf16_rtne(w1.y);
        pkw[6] = f32_to_bf16_rtne(w1.z); pkw[7] = f32_to_bf16_rtne(w1.w);
        *reinterpret_cast<short8v*>(&wB[r * KP + c8 * 8]) = pkw;
    }
    __syncthreads();

    const int w  = t >> 6;    // wave id
    const int l  = t & 63;
    const int lr = l & 15;    // A row / B col / C col within 16
    const int lk = l >> 4;    // k-group (0..3)

    float4v acc[4] = {{0.f,0.f,0.f,0.f},{0.f,0.f,0.f,0.f},
                      {0.f,0.f,0.f,0.f},{0.f,0.f,0.f,0.f}};

    for (int kk = 0; kk < 8; ++kk) {                 // K-steps of 32
        const int kbase = kk * 32 + lk * 8;
        const short8v a = *reinterpret_cast<const short8v*>(&hA[(w * 16 + lr) * KP + kbase]);
#pragma unroll
        for (int n = 0; n < 4; ++n) {
            const short8v b = *reinterpret_cast<const short8v*>(&wB[(n * 16 + lr) * KP + kbase]);
            acc[n] = __builtin_amdgcn_mfma_f32_16x16x32_bf16(a, b, acc[n], 0, 0, 0);
        }
    }

    // ---- epilogue: write z (f32), fused s/d logits ----
    float as[4], ad[4];
#pragma unroll
    for (int n = 0; n < 4; ++n) {
        as[n] = A[n * 16 + lr];
        ad[n] = A[N_OUT + n * 16 + lr];
    }

    float sv[4] = {0.f,0.f,0.f,0.f}, dv[4] = {0.f,0.f,0.f,0.f};
#pragma unroll
    for (int n = 0; n < 4; ++n) {
#pragma unroll
        for (int r = 0; r < 4; ++r) {
            const float v = acc[n][r];
            const int grow = row0 + w * 16 + lk * 4 + r;
            if (grow < n_nodes) z[(size_t)grow * N_OUT + n * 16 + lr] = v;
            sv[r] = fmaf(v, as[n], sv[r]);
            dv[r] = fmaf(v, ad[n], dv[r]);
        }
    }
    // reduce over the 16 lanes (lr) of each lk-group
#pragma unroll
    for (int off = 1; off < 16; off <<= 1) {
#pragma unroll
        for (int r = 0; r < 4; ++r) {
            sv[r] += __shfl_xor(sv[r], off);
            dv[r] += __shfl_xor(dv[r], off);
        }
    }
    if (lr == 0) {
#pragma unroll
        for (int r = 0; r < 4; ++r) {
            const int grow = row0 + w * 16 + lk * 4 + r;
            if (grow < n_nodes) { s_node[grow] = sv[r]; d_node[grow] = dv[r]; }
        }
    }
}

// ---------------------------------------------------------------------------
// Kernel 2: histogram of dst  (counts must be pre-zeroed)
// ---------------------------------------------------------------------------
__global__ __launch_bounds__(256) void count_dst(
    const int* __restrict__ dst, int* __restrict__ counts, int n_edges)
{
    int i = blockIdx.x * blockDim.x + threadIdx.x;
    const int stride = gridDim.x * blockDim.x;
    for (; i < n_edges; i += stride)
        atomicAdd(&counts[dst[i]], 1);
}

// ---------------------------------------------------------------------------
// Kernel 3a: per-block exclusive scan (in-place) + block totals
// ---------------------------------------------------------------------------
__global__ __launch_bounds__(1024) void scan_block(
    int* __restrict__ data, int* __restrict__ partials, int n)
{
    __shared__ int tmp[1024];
    const int gid = blockIdx.x * 1024 + threadIdx.x;
    const int v = (gid < n) ? data[gid] : 0;
    tmp[threadIdx.x] = v;
    __syncthreads();
    for (int off = 1; off < 1024; off <<= 1) {
        int t = (threadIdx.x >= off) ? tmp[threadIdx.x - off] : 0;
        __syncthreads();
        tmp[threadIdx.x] += t;
        __syncthreads();
    }
    const int incl = tmp[threadIdx.x];
    if (gid < n) data[gid] = incl - v;               // exclusive within block
    if (threadIdx.x == 1023) partials[blockIdx.x] = incl;
}

// Kernel 3b: exclusive scan of block totals (single block, nb <= 128)
__global__ __launch_bounds__(128) void scan_partials(int* __restrict__ partials, int nb)
{
    __shared__ int tmp[128];
    const int v = (threadIdx.x < nb) ? partials[threadIdx.x] : 0;
    tmp[threadIdx.x] = v;
    __syncthreads();
    for (int off = 1; off < 128; off <<= 1) {
        int t = (threadIdx.x >= off) ? tmp[threadIdx.x - off] : 0;
        __syncthreads();
        tmp[threadIdx.x] += t;
        __syncthreads();
    }
    if (threadIdx.x < nb) partials[threadIdx.x] = tmp[threadIdx.x] - v;
}

// Kernel 3c: add scanned block bases -> full exclusive scan (segment starts)
__global__ __launch_bounds__(256) void scan_add_base(
    int* __restrict__ data, const int* __restrict__ partials, int n)
{
    const int gid = blockIdx.x * blockDim.x + threadIdx.x;
    if (gid < n) data[gid] += partials[gid >> 10];
}

// ---------------------------------------------------------------------------
// Kernel 4: compute p = exp(leakyrelu(s[src]+d[dst])) and scatter {src,p}
// into dst-sorted order. cursor[] starts as segment starts; after this
// kernel cursor[d] == segment end of d (exclusive).
// ---------------------------------------------------------------------------
__global__ __launch_bounds__(256) void edge_scatter(
    const int* __restrict__ src, const int* __restrict__ dst,
    const float* __restrict__ s_node, const float* __restrict__ d_node,
    int* __restrict__ cursor, int2* __restrict__ edges, int n_edges)
{
    int i = blockIdx.x * blockDim.x + threadIdx.x;
    const int stride = gridDim.x * blockDim.x;
    for (; i < n_edges; i += stride) {
        const int s = src[i], d = dst[i];
        float e = s_node[s] + d_node[d];
        e = (e >= 0.f) ? e : NEG_SLOPE * e;
        const float pe = __expf(e);
        const int pos = atomicAdd(&cursor[d], 1);
        edges[pos] = make_int2(s, __float_as_int(pe));
    }
}

// ---------------------------------------------------------------------------
// Kernel 5: one wave per dst node; 16 lanes per edge, 4 edges in flight.
// sub = lane>>4 owns edge slot; lane&15 owns a float4 of the z row.
// Butterfly xor(16,32) reduces across the 4 edge slots at the end.
// ---------------------------------------------------------------------------
__global__ __launch_bounds__(256) void gather_accum(
    const int2* __restrict__ edges, const int* __restrict__ segend,
    const float* __restrict__ z, float* __restrict__ out, int n_nodes)
{
    const int wave = (blockIdx.x * 256 + threadIdx.x) >> 6;
    const int lane = threadIdx.x & 63;
    if (wave >= n_nodes) return;
    const int sub = lane >> 4;   // edge slot 0..3
    const int l16 = lane & 15;   // float4 index within row
    const int end   = segend[wave];
    const int start = (wave == 0) ? 0 : segend[wave - 1];

    float ax = 0.f, ay = 0.f, az = 0.f, aw = 0.f, denom = 0.f;
    int i = start + sub;
    // 2x unroll: 8 z-rows in flight per wave
    for (; i + 4 < end; i += 8) {
        const int2 e0 = edges[i];
        const int2 e1 = edges[i + 4];
        const float4 z0 = reinterpret_cast<const float4*>(z + (size_t)e0.x * N_OUT)[l16];
        const float4 z1 = reinterpret_cast<const float4*>(z + (size_t)e1.x * N_OUT)[l16];
        const float p0 = __int_as_float(e0.y);
        const float p1 = __int_as_float(e1.y);
        denom += p0 + p1;
        ax = fmaf(p0, z0.x, ax); ay = fmaf(p0, z0.y, ay);
        az = fmaf(p0, z0.z, az); aw = fmaf(p0, z0.w, aw);
        ax = fmaf(p1, z1.x, ax); ay = fmaf(p1, z1.y, ay);
        az = fmaf(p1, z1.z, az); aw = fmaf(p1, z1.w, aw);
    }
    if (i < end) {
        const int2 e0 = edges[i];
        const float4 z0 = reinterpret_cast<const float4*>(z + (size_t)e0.x * N_OUT)[l16];
        const float p0 = __int_as_float(e0.y);
        denom += p0;
        ax = fmaf(p0, z0.x, ax); ay = fmaf(p0, z0.y, ay);
        az = fmaf(p0, z0.z, az); aw = fmaf(p0, z0.w, aw);
    }
    // reduce across the 4 edge slots (lanes l16, l16+16, l16+32, l16+48)
#pragma unroll
    for (int off = 16; off < 64; off <<= 1) {
        ax += __shfl_xor(ax, off);
        ay += __shfl_xor(ay, off);
        az += __shfl_xor(az, off);
        aw += __shfl_xor(aw, off);
        denom += __shfl_xor(denom, off);
    }
    if (sub == 0) {
        const float inv = (end > start) ? 1.f / denom : 0.f;
        float4 r;
        r.x = ax * inv; r.y = ay * inv; r.z = az * inv; r.w = aw * inv;
        reinterpret_cast<float4*>(out + (size_t)wave * N_OUT)[l16] = r;
    }
}

// ---------------------------------------------------------------------------
extern "C" void kernel_launch(void* const* d_in, const int* in_sizes, int n_in,
                              void* d_out, int out_size, void* d_ws, size_t ws_size,
                              hipStream_t stream) {
    const float* h = (const float*)d_in[0];
    const float* W = (const float*)d_in[1];
    const float* A = (const float*)d_in[2];
    const int* src = (const int*)d_in[3];
    const int* dst = (const int*)d_in[4];
    float* out = (float*)d_out;

    const int n_nodes = in_sizes[0] / N_IN;
    const int n_edges = in_sizes[3];

    // workspace layout (all offsets keep 8B alignment for the int2 array)
    char* ws = (char*)d_ws;
    float* z      = (float*)ws;                    ws += (size_t)n_nodes * N_OUT * 4;
    float* s_node = (float*)ws;                    ws += (size_t)n_nodes * 4;
    float* d_node = (float*)ws;                    ws += (size_t)n_nodes * 4;
    int*   counts = (int*)ws;                      ws += (size_t)n_nodes * 4;   // -> offsets -> segends
    int*   parts  = (int*)ws;                      ws += 512;
    int2*  edges  = (int2*)ws;

    const int nb_scan = (n_nodes + 1023) / 1024;   // 98 <= 128

    // zero the histogram only (kernel 5 writes every out element)
    hipMemsetAsync(counts, 0, (size_t)n_nodes * sizeof(int), stream);

    // 1) GEMM + logits (bf16 MFMA)
    gemm_zsd_mfma<<<(n_nodes + GM - 1) / GM, 256, 0, stream>>>(h, W, A, z, s_node, d_node, n_nodes);

    // 2) dst histogram
    count_dst<<<1024, 256, 0, stream>>>(dst, counts, n_edges);

    // 3) exclusive scan -> segment starts
    scan_block<<<nb_scan, 1024, 0, stream>>>(counts, parts, n_nodes);
    scan_partials<<<1, 128, 0, stream>>>(parts, nb_scan);
    scan_add_base<<<(n_nodes + 255) / 256, 256, 0, stream>>>(counts, parts, n_nodes);

    // 4) compute p and scatter into dst-sorted order (counts -> segment ends)
    edge_scatter<<<2048, 256, 0, stream>>>(src, dst, s_node, d_node, counts, edges, n_edges);

    // 5) per-dst register accumulate, single write of out
    gather_accum<<<(n_nodes * 64 + 255) / 256, 256, 0, stream>>>(edges, counts, z, out, n_nodes);
}